// Round 1
// 144.281 us; speedup vs baseline: 1.0397x; 1.0397x over previous
//
#include <hip/hip_runtime.h>
#include <hip/hip_bf16.h>

#define NB 2
#define SEQ 2048
#define DM 384
#define NH 8
#define HD 48
#define QKVN 1152

typedef __hip_bfloat16 bf16;
typedef __attribute__((ext_vector_type(8))) short short8;
typedef __attribute__((ext_vector_type(4))) float float4v;
typedef __attribute__((ext_vector_type(16))) float f32x16;

static __device__ __forceinline__ float bf2f(bf16 v){ return __bfloat162float(v); }
static __device__ __forceinline__ float ldin(const void* p, size_t i, int isf){
    return isf ? ((const float*)p)[i] : bf2f(((const bf16*)p)[i]);
}
// fp32 -> bf16 bits, RNE
static __device__ __forceinline__ short f2b(float f){
    union { float f; unsigned u; } a; a.f = f;
    unsigned r = a.u + 0x7FFFu + ((a.u >> 16) & 1u);
    return (short)(r >> 16);
}
// packed fp32x2 -> bf16x2 (v_cvt_pk_bf16_f32)
static __device__ __forceinline__ unsigned pk2(float a, float b){
    union { __hip_bfloat162 h; unsigned u; } r;
    r.h = __float22bfloat162_rn(float2{a, b});
    return r.u;
}
static __device__ __forceinline__ float bflo(unsigned u){
    union { unsigned u; float f; } a; a.u = u << 16; return a.f;
}
static __device__ __forceinline__ float bfhi(unsigned u){
    union { unsigned u; float f; } a; a.u = u & 0xFFFF0000u; return a.f;
}
static __device__ __forceinline__ short8 u4pack(unsigned w0, unsigned w1, unsigned w2, unsigned w3){
    union { unsigned u[4]; short8 s; } r; r.u[0]=w0; r.u[1]=w1; r.u[2]=w2; r.u[3]=w3; return r.s;
}
// per-block input dtype probe (0 = bf16, 1 = fp32); wave-uniform
static __device__ __forceinline__ int detect_isf(const void* x){
    const unsigned short* xb = (const unsigned short*)x;
    int l = threadIdx.x & 63;
    union { unsigned u; float f; } a; a.u = ((unsigned)xb[2*l]) << 16;
    float ab = fabsf(a.f);
    int good = (a.f == 0.0f) || (ab > 9.765625e-4f && ab < 1024.0f);
    unsigned long long m = __ballot(good);
    return (__popcll(m) >= 32) ? 0 : 1;
}

// ---------------- K_prep
// dist8 layout (v2, for 32x32 MFMA consumption): [b][jg = j>>2 (512)][i(2048)][jj(4)] bf16
__global__ __launch_bounds__(256) void k_prep(const void* __restrict__ x,
    const void* __restrict__ coords,
    const void* __restrict__ Wqkv, const void* __restrict__ Wout,
    const void* __restrict__ bqkv, const void* __restrict__ bout,
    const void* __restrict__ Wdist, const void* __restrict__ bdist,
    short* __restrict__ dist8, short* __restrict__ xb,
    short* __restrict__ WqT, short* __restrict__ WoT,
    float* __restrict__ bqf, float* __restrict__ bof,
    float* __restrict__ wdf, float* __restrict__ bdf)
{
    const int isf = detect_isf(x);
    const int t = threadIdx.x;
    const int b = blockIdx.x;
    if (b < 512) {
        const int bb = b >> 8;               // batch
        const int jg = (b >> 1) & 127;       // 16-j group
        const int j0 = jg * 16;
        const int ih = (b & 1) * 1024;       // i-half
        __shared__ float cjx[16], cjy[16], cjz[16];
        if (t < 16) {
            int gj = (bb*SEQ + j0 + t)*3;
            cjx[t] = ldin(coords, gj, isf);
            cjy[t] = ldin(coords, gj+1, isf);
            cjz[t] = ldin(coords, gj+2, isf);
        }
        __syncthreads();
        #pragma unroll
        for (int k = 0; k < 4; ++k) {
            int i = ih + k*256 + t;
            int gi = (bb*SEQ + i)*3;
            float px = ldin(coords, gi, isf), py = ldin(coords, gi+1, isf), pz = ldin(coords, gi+2, isf);
            short o[16];
            #pragma unroll
            for (int e = 0; e < 16; ++e) {
                float dx = px - cjx[e], dy = py - cjy[e], dz = pz - cjz[e];
                o[e] = f2b(sqrtf(dx*dx + dy*dy + dz*dz));
            }
            // 4 groups of 4 j each: [b][jg*4+g][i][4]
            short* dst = dist8 + (((size_t)bb*512 + (size_t)jg*4)*SEQ + i)*4;
            *(int2*)(dst)          = *(const int2*)(o);
            *(int2*)(dst + SEQ*4)  = *(const int2*)(o + 4);
            *(int2*)(dst + SEQ*8)  = *(const int2*)(o + 8);
            *(int2*)(dst + SEQ*12) = *(const int2*)(o + 12);
        }
    } else if (b < 1280) {
        size_t i = ((size_t)(b-512)*256 + t)*8;
        if (isf) {
            const float* xf = (const float*)x + i;
            short o[8];
            #pragma unroll
            for (int e = 0; e < 8; ++e) o[e] = f2b(xf[e]);
            *(int4*)(xb + i) = *(const int4*)o;
        } else {
            *(int4*)(xb + i) = *(const int4*)((const short*)x + i);
        }
    } else if (b < 1856) {
        int bb, NW; const void* W; short* WT;
        if (b < 1712) { bb = b - 1280; NW = QKVN; W = Wqkv; WT = WqT; }
        else          { bb = b - 1712; NW = DM;   W = Wout; WT = WoT; }
        int ntiles = NW >> 5;
        int kt = bb / ntiles, nt = bb % ntiles;
        int k0 = kt*32, n0 = nt*32;
        __shared__ float Ls[32][33];
        for (int idx = t; idx < 1024; idx += 256) {
            int r = idx >> 5, c = idx & 31;
            Ls[r][c] = ldin(W, (size_t)(k0+r)*NW + n0 + c, isf);
        }
        __syncthreads();
        for (int idx = t; idx < 1024; idx += 256) {
            int r2 = idx >> 5, c2 = idx & 31;
            WT[(size_t)(n0+r2)*DM + k0 + c2] = f2b(Ls[c2][r2]);
        }
    } else {
        int idx = (b - 1856)*256 + t;
        const float log2e = 1.4426950408889634f;
        if (idx < QKVN) bqf[idx] = ldin(bqkv, idx, isf);
        else if (idx < QKVN + DM) bof[idx - QKVN] = ldin(bout, idx - QKVN, isf);
        else if (idx < QKVN + DM + NH) wdf[idx - QKVN - DM] = ldin(Wdist, idx - QKVN - DM, isf)*log2e;
        else if (idx < QKVN + DM + 2*NH) bdf[idx - QKVN - DM - NH] = ldin(bdist, idx - QKVN - DM - NH, isf)*log2e;
    }
}

// ---------------- K1: MFMA GEMM qkv = xb @ Wqkv + b; scatter to 32x32x16 frag layouts
// qg3/kg3: [bh][t32(64)][dc(3)][hi(2)][tok(32)][e(8)]  elem = X[tok][dc*16 + hi*8 + e]
//          (A-row / B-col = lane&31 = tok; (hi,e) slot order identical on both operands
//           -> k-map agnostic). 1536 shorts / 32-token tile.
// vg3:     [bh][jt(64)][jc(2)]{ dt0:[hi][32 d][e8] , dt1:[hi][16 d][e8] } 1536 s/tile.
//          slot (hi,e) holds token j = jc*16 + (e&3) + 8*(e>>2) + 4*hi  (the verified 32x32
//          C-row order) so PV's A-operand is the raw sacc register order — no cross-lane.
__global__ __launch_bounds__(256) void k_qkv(const short* __restrict__ xb,
    const short* __restrict__ WT, const float* __restrict__ bias,
    short* __restrict__ qg3, short* __restrict__ kg3, short* __restrict__ vg3)
{
    __shared__ __align__(16) short As[64*72];
    __shared__ __align__(16) short Bs[128*72];   // reused as epilogue buffer
    const int t = threadIdx.x;
    const int w = t >> 6, lane = t & 63, L = lane & 15, quad = lane >> 4;
    const int mt = blockIdx.x / 9, nt = blockIdx.x % 9;
    const int row0 = mt*64, col0 = nt*128;
    const int wm = w & 1, wn = w >> 1;
    float4v acc[2][4] = {};
    for (int k0 = 0; k0 < DM; k0 += 64) {
        __syncthreads();
        for (int c = t; c < 512; c += 256) {
            int row = c >> 3, k8 = c & 7;
            *(int4*)(&As[row*72 + k8*8]) = *(const int4*)(xb + (size_t)(row0+row)*DM + k0 + k8*8);
        }
        for (int c = t; c < 1024; c += 256) {
            int row = c >> 3, k8 = c & 7;
            *(int4*)(&Bs[row*72 + k8*8]) = *(const int4*)(WT + (size_t)(col0+row)*DM + k0 + k8*8);
        }
        __syncthreads();
        #pragma unroll
        for (int kc = 0; kc < 2; ++kc) {
            short8 a0 = *(const short8*)(&As[(32*wm + L)*72 + kc*32 + quad*8]);
            short8 a1 = *(const short8*)(&As[(32*wm + 16 + L)*72 + kc*32 + quad*8]);
            #pragma unroll
            for (int ni = 0; ni < 4; ++ni) {
                short8 bf = *(const short8*)(&Bs[(64*wn + 16*ni + L)*72 + kc*32 + quad*8]);
                acc[0][ni] = __builtin_amdgcn_mfma_f32_16x16x32_bf16(a0, bf, acc[0][ni], 0, 0, 0);
                acc[1][ni] = __builtin_amdgcn_mfma_f32_16x16x32_bf16(a1, bf, acc[1][ni], 0, 0, 0);
            }
        }
    }
    const int which = col0 / DM;     // uniform per block (0=q,1=k,2=v)
    const int cbase = col0 % DM;
    short* Ep = Bs;
    __syncthreads();
    if (which < 2) {
        // row-major Ep[64 tokens][136]
        #pragma unroll
        for (int mi = 0; mi < 2; ++mi)
            #pragma unroll
            for (int ni = 0; ni < 4; ++ni) {
                int col_l = 64*wn + 16*ni + L;
                float bv = bias[col0 + col_l];
                #pragma unroll
                for (int r = 0; r < 4; ++r) {
                    int row_l = 32*wm + 16*mi + quad*4 + r;
                    Ep[row_l*136 + col_l] = f2b(acc[mi][ni][r] + bv);
                }
            }
        __syncthreads();
        short* dst = which ? kg3 : qg3;
        for (int c = t; c < 1024; c += 256) {
            int row_l = c >> 4, col_l = (c & 15)*8;   // 8 consecutive d, one token
            int row_g = row0 + row_l;
            int bi = row_g >> 11, nn = row_g & (SEQ-1);
            int c2 = cbase + col_l;
            int hh = c2/HD, dh = c2%HD;
            int bh = bi*NH + hh;
            int dc = dh >> 4, hi = (dh >> 3) & 1;
            size_t dstoff = ((size_t)bh*64 + (nn>>5))*1536 + (size_t)((dc*2 + hi)*256 + (nn&31)*8);
            *(int4*)(dst + dstoff) = *(const int4*)(&Ep[row_l*136 + col_l]);
        }
    } else {
        // col-major Ep[128 cols][72 tokens]
        #pragma unroll
        for (int mi = 0; mi < 2; ++mi)
            #pragma unroll
            for (int ni = 0; ni < 4; ++ni) {
                int col_l = 64*wn + 16*ni + L;
                float bv = bias[col0 + col_l];
                #pragma unroll
                for (int r = 0; r < 4; ++r) {
                    int row_l = 32*wm + 16*mi + quad*4 + r;
                    Ep[col_l*72 + row_l] = f2b(acc[mi][ni][r] + bv);
                }
            }
        __syncthreads();
        for (int c = t; c < 1024; c += 256) {
            int col_l = c >> 3, row8 = (c & 7)*8;     // 8 consecutive tokens, one d
            int row_g = row0 + row8;
            int bi = row_g >> 11, nn = row_g & (SEQ-1);
            int c2 = cbase + col_l;
            int hh = c2/HD, dh = c2%HD;
            int bh = bi*NH + hh;
            int jt = nn >> 5, jc = (nn >> 4) & 1;
            int ehalf = ((nn >> 3) & 1)*4;            // e>>2 half of the slot
            int dt = dh >> 5, dp = dh & 31;           // d-tile 0: 32 cols, d-tile 1: 16 cols
            int hstride = dt ? 128 : 256;
            size_t base = ((size_t)bh*64 + jt)*1536 + (size_t)(jc*768 + dt*512 + dp*8 + ehalf);
            // tokens nn..nn+3 -> slot hi=0, tokens nn+4..nn+7 -> slot hi=1
            *(int2*)(vg3 + base)           = *(const int2*)(&Ep[col_l*72 + row8]);
            *(int2*)(vg3 + base + hstride) = *(const int2*)(&Ep[col_l*72 + row8 + 4]);
        }
    }
}

// ---------------- K2: flash attention on 32x32x16 MFMA
// Block = 4 waves sharing one 32-i tile; wave w handles j-tiles (4s+w), s=0..15.
// QK^T: 3 pad-free K=16 chunks (d=48). sacc C-layout (verified m74/m101):
//   i = lane&31, j = (reg&3) + 8*(reg>>2) + 4*(lane>>5).
// PV: pa = sacc-order p packed via cvt_pk (V slot order permuted at prep time to match),
//   accO0 = d 0..31, accO1 = d 32..47 (cols 16..31 of accO1 are garbage, never stored).
// Swizzle: bid%8 chunks -> each XCD gets all 16 bh of an 8-it band: dist8 slices (shared
// across the 8 heads) get 8x in-L2 reuse instead of 8x L3 refetch.
__global__ __launch_bounds__(256, 4) void k_attn(
    const short* __restrict__ qg3, const short* __restrict__ kg3, const short* __restrict__ vg3,
    const short* __restrict__ dist8, const float* __restrict__ wdf,
    const float* __restrict__ bdf, short* __restrict__ aob)
{
    __shared__ float Ored[2][32*48];
    __shared__ float Lred[2][32];
    const int t = threadIdx.x;
    const int w = t >> 6, lane = t & 63;
    const int li = lane & 31, hi = lane >> 5;
    const int bid = blockIdx.x;
    const int lg = (bid & 7)*128 + (bid >> 3);   // bijective: 1024 % 8 == 0
    const int hh = lg & 7;
    const int rest = lg >> 3;
    const int bi = rest & 1, it = rest >> 1;
    const int bh = bi*NH + hh;
    const int i0 = it*32;
    const float scale2 = 0.14433756729740643f * 1.4426950408889634f;
    const float wd = wdf[hh], bd = bdf[hh];     // pre-scaled by log2e

    const short* qB = qg3 + ((size_t)bh*64 + it)*1536 + hi*256 + li*8;
    const short8 qf0 = *(const short8*)(qB);
    const short8 qf1 = *(const short8*)(qB + 512);
    const short8 qf2 = *(const short8*)(qB + 1024);

    f32x16 accO0 = {}, accO1 = {};
    float rsum = 0.0f;

    const short* kBp = kg3 + ((size_t)bh*64 + w)*1536 + hi*256 + li*8;
    const short* vBp = vg3 + ((size_t)bh*64 + w)*1536 + li*8;
    const short* dBp = dist8 + (((size_t)bi*512 + (size_t)w*8 + hi)*SEQ + i0 + li)*4;

    for (int s = 0; s < 16; ++s) {
        short8 kf0 = *(const short8*)(kBp);
        short8 kf1 = *(const short8*)(kBp + 512);
        short8 kf2 = *(const short8*)(kBp + 1024);
        int2 du0 = *(const int2*)(dBp);
        int2 du1 = *(const int2*)(dBp + SEQ*8);
        int2 du2 = *(const int2*)(dBp + SEQ*16);
        int2 du3 = *(const int2*)(dBp + SEQ*24);
        f32x16 sacc = {};
        sacc = __builtin_amdgcn_mfma_f32_32x32x16_bf16(kf0, qf0, sacc, 0, 0, 0);
        sacc = __builtin_amdgcn_mfma_f32_32x32x16_bf16(kf1, qf1, sacc, 0, 0, 0);
        sacc = __builtin_amdgcn_mfma_f32_32x32x16_bf16(kf2, qf2, sacc, 0, 0, 0);
        float p[16];
        #pragma unroll
        for (int rq = 0; rq < 4; ++rq) {
            int2 du = rq == 0 ? du0 : rq == 1 ? du1 : rq == 2 ? du2 : du3;
            float d0 = bflo((unsigned)du.x), d1 = bfhi((unsigned)du.x);
            float d2 = bflo((unsigned)du.y), d3 = bfhi((unsigned)du.y);
            p[4*rq+0] = __builtin_amdgcn_exp2f(fmaf(sacc[4*rq+0], scale2, fmaf(d0, wd, bd)));
            p[4*rq+1] = __builtin_amdgcn_exp2f(fmaf(sacc[4*rq+1], scale2, fmaf(d1, wd, bd)));
            p[4*rq+2] = __builtin_amdgcn_exp2f(fmaf(sacc[4*rq+2], scale2, fmaf(d2, wd, bd)));
            p[4*rq+3] = __builtin_amdgcn_exp2f(fmaf(sacc[4*rq+3], scale2, fmaf(d3, wd, bd)));
            rsum += (p[4*rq+0] + p[4*rq+1]) + (p[4*rq+2] + p[4*rq+3]);
        }
        short8 pa0 = u4pack(pk2(p[0],p[1]),  pk2(p[2],p[3]),  pk2(p[4],p[5]),   pk2(p[6],p[7]));
        short8 pa1 = u4pack(pk2(p[8],p[9]),  pk2(p[10],p[11]),pk2(p[12],p[13]), pk2(p[14],p[15]));
        short8 v00 = *(const short8*)(vBp + hi*256);            // jc0, d 0..31
        short8 v10 = *(const short8*)(vBp + 768 + hi*256);      // jc1, d 0..31
        accO0 = __builtin_amdgcn_mfma_f32_32x32x16_bf16(pa0, v00, accO0, 0, 0, 0);
        accO0 = __builtin_amdgcn_mfma_f32_32x32x16_bf16(pa1, v10, accO0, 0, 0, 0);
        short8 v01 = *(const short8*)(vBp + 512 + hi*128);      // jc0, d 32..47 (cols>=16 garbage)
        short8 v11 = *(const short8*)(vBp + 1280 + hi*128);     // jc1, d 32..47
        accO1 = __builtin_amdgcn_mfma_f32_32x32x16_bf16(pa0, v01, accO1, 0, 0, 0);
        accO1 = __builtin_amdgcn_mfma_f32_32x32x16_bf16(pa1, v11, accO1, 0, 0, 0);
        kBp += 4*1536; vBp += 4*1536; dBp += (size_t)SEQ*128;
    }
    rsum += __shfl_xor(rsum, 32);   // partner half-lane holds the other 16 j per tile

    // cross-wave tree reduction
    if (w >= 2) {
        float* Od = Ored[w-2];
        #pragma unroll
        for (int r = 0; r < 16; ++r) {
            int ii = (r & 3) + 8*(r >> 2) + 4*hi;
            Od[ii*48 + li] = accO0[r];
            if (li < 16) Od[ii*48 + 32 + li] = accO1[r];
        }
        if (lane < 32) Lred[w-2][lane] = rsum;
    }
    __syncthreads();
    if (w < 2) {
        const float* Od = Ored[w];
        #pragma unroll
        for (int r = 0; r < 16; ++r) {
            int ii = (r & 3) + 8*(r >> 2) + 4*hi;
            accO0[r] += Od[ii*48 + li];
            accO1[r] += Od[ii*48 + 32 + (li & 15)];
        }
        rsum += Lred[w][li];
    }
    __syncthreads();
    if (w == 1) {
        float* Od = Ored[0];
        #pragma unroll
        for (int r = 0; r < 16; ++r) {
            int ii = (r & 3) + 8*(r >> 2) + 4*hi;
            Od[ii*48 + li] = accO0[r];
            if (li < 16) Od[ii*48 + 32 + li] = accO1[r];
        }
        if (lane < 32) Lred[0][lane] = rsum;
    }
    __syncthreads();
    if (w == 0) {
        float* Od = Ored[0];
        #pragma unroll
        for (int r = 0; r < 16; ++r) {
            int ii = (r & 3) + 8*(r >> 2) + 4*hi;
            Od[ii*48 + li] += accO0[r];
            if (li < 16) Od[ii*48 + 32 + li] += accO1[r];
        }
        if (lane < 32) Lred[0][lane] += rsum;
    }
    __syncthreads();
    // all waves: normalize + coalesced int4 store of the 32x48 tile
    for (int c = t; c < 192; c += 256) {
        int r = c / 6, d8 = (c % 6)*8;
        float inv = 1.0f / Lred[0][r];
        const float* src = &Ored[0][r*48 + d8];
        short o[8];
        #pragma unroll
        for (int e = 0; e < 8; ++e) o[e] = f2b(src[e]*inv);
        *(int4*)(aob + ((size_t)(bi*SEQ) + i0 + r)*DM + hh*HD + d8) = *(const int4*)o;
    }
}

// ---------------- K3: MFMA GEMM out = aob @ Wout + b_out
__global__ __launch_bounds__(256) void k_out(const short* __restrict__ aob,
    const short* __restrict__ WT, const float* __restrict__ bias,
    void* __restrict__ out, const void* __restrict__ x)
{
    __shared__ __align__(16) short As[64*72];
    __shared__ __align__(16) short Bs[128*72];
    const int isf = detect_isf(x);
    const int t = threadIdx.x;
    const int w = t >> 6, lane = t & 63, L = lane & 15, quad = lane >> 4;
    const int mt = blockIdx.x / 3, nt = blockIdx.x % 3;
    const int row0 = mt*64, col0 = nt*128;
    const int wm = w & 1, wn = w >> 1;
    float4v acc[2][4] = {};
    for (int k0 = 0; k0 < DM; k0 += 64) {
        __syncthreads();
        for (int c = t; c < 512; c += 256) {
            int row = c >> 3, k8 = c & 7;
            *(int4*)(&As[row*72 + k8*8]) = *(const int4*)(aob + (size_t)(row0+row)*DM + k0 + k8*8);
        }
        for (int c = t; c < 1024; c += 256) {
            int row = c >> 3, k8 = c & 7;
            *(int4*)(&Bs[row*72 + k8*8]) = *(const int4*)(WT + (size_t)(col0+row)*DM + k0 + k8*8);
        }
        __syncthreads();
        #pragma unroll
        for (int kc = 0; kc < 2; ++kc) {
            short8 a0 = *(const short8*)(&As[(32*wm + L)*72 + kc*32 + quad*8]);
            short8 a1 = *(const short8*)(&As[(32*wm + 16 + L)*72 + kc*32 + quad*8]);
            #pragma unroll
            for (int ni = 0; ni < 4; ++ni) {
                short8 bf = *(const short8*)(&Bs[(64*wn + 16*ni + L)*72 + kc*32 + quad*8]);
                acc[0][ni] = __builtin_amdgcn_mfma_f32_16x16x32_bf16(a0, bf, acc[0][ni], 0, 0, 0);
                acc[1][ni] = __builtin_amdgcn_mfma_f32_16x16x32_bf16(a1, bf, acc[1][ni], 0, 0, 0);
            }
        }
    }
    #pragma unroll
    for (int mi = 0; mi < 2; ++mi) {
        #pragma unroll
        for (int ni = 0; ni < 4; ++ni) {
            int col_g = col0 + 64*wn + 16*ni + L;
            float bv = bias[col_g];
            #pragma unroll
            for (int r = 0; r < 4; ++r) {
                int row_g = row0 + 32*wm + 16*mi + quad*4 + r;
                size_t oi = (size_t)row_g*DM + col_g;
                float val = acc[mi][ni][r] + bv;
                if (isf) ((float*)out)[oi] = val;
                else     ((bf16*)out)[oi]  = __float2bfloat16(val);
            }
        }
    }
}

extern "C" void kernel_launch(void* const* d_in, const int* in_sizes, int n_in,
                              void* d_out, int out_size, void* d_ws, size_t ws_size,
                              hipStream_t stream) {
    const void* x      = d_in[0];
    const void* coords = d_in[1];
    const void* Wqkv   = d_in[2];
    const void* bqkv   = d_in[3];
    const void* Wdist  = d_in[4];
    const void* bdist  = d_in[5];
    const void* Wout   = d_in[6];
    const void* bout   = d_in[7];

    short* qg3   = (short*)d_ws;                       // 16*64*1536 = 1,572,864
    short* kg3   = qg3  + (size_t)1572864;             // 1,572,864
    short* vg3   = kg3  + (size_t)1572864;             // 1,572,864 + 256 overread pad
    short* dist8 = vg3  + (size_t)1573120;             // 2*512*2048*4 = 8,388,608
    short* aob   = dist8 + (size_t)8388608;            // 1,572,864
    short* xb    = aob  + (size_t)1572864;             // 1,572,864
    short* WqT   = xb   + (size_t)1572864;             // 442,368
    short* WoT   = WqT  + (size_t)442368;              // 147,456
    float* bqf   = (float*)(WoT + (size_t)147456);
    float* bof   = bqf + QKVN;
    float* wdf   = bof + DM;
    float* bdf   = wdf + NH;

    k_prep<<<dim3(1863), dim3(256), 0, stream>>>(x, coords, Wqkv, Wout, bqkv, bout,
                                                 Wdist, bdist, dist8, xb, WqT, WoT,
                                                 bqf, bof, wdf, bdf);
    k_qkv<<<dim3(64*9), dim3(256), 0, stream>>>(xb, WqT, bqf, qg3, kg3, vg3);
    k_attn<<<dim3(16*64), dim3(256), 0, stream>>>(qg3, kg3, vg3, dist8, wdf, bdf, aob);
    k_out<<<dim3(64*3), dim3(256), 0, stream>>>(aob, WoT, bof, d_out, x);
}